// Round 2
// 2329.459 us; speedup vs baseline: 1.0719x; 1.0719x over previous
//
#include <hip/hip_runtime.h>

// 2-layer LSTM encoder, fused single kernel, v6b (= v6 with update_dpp spelling;
// round-1 bench was an infra container failure, no counter data).
//
// ROUND-5 THEORY: v5 step latency 1460 cyc; ~64% is LDS return-path beats from
// uniform-broadcast ds_read_b128 (116/step/CU; broadcast is conflict-free but
// pays full 64-lane x 16B return bandwidth), plus __syncthreads' vmcnt(0)
// drain putting the per-step global out-store (~300 cyc ack) in the chain.
//
// v6 restructure:
//  * K-split dots: L1 quad-per-unit (lane = 4*u + kq; 4 gates x 17 FMAs over
//    K-quarter; reads 4xb128 + 1xb32). L2 octet-per-unit over a CONCATENATED
//    hbuf[ring][96] = [h1(64), h2(32)] (lane = 8*u + m; 4 gates x 12 FMAs;
//    reads 3xb128). LDS beats/step drop ~4x.
//  * Partial sums combined with full-rate DPP butterflies (quad_perm xor1/xor2;
//    row_shl4/row_shr4 + cndmask for the xor4 stage). No ds_bpermute anywhere;
//    after the all-reduce every lane holds all 4 gates (i,f,g,o) -> uniform
//    activation code, c/h kept redundantly per group, kq==0 / m==0 writes.
//  * Raw s_barrier + s_waitcnt lgkmcnt(0) (no vmcnt drain): out-stores and the
//    x prefetch stream freely.
//  * Ring parity: at iter n, both layers read hbuf[(n+1)&1] (h1(n-1), h2(n-2))
//    and write hbuf[n&1] (h1(n) at [0..63], h2(n-1) at [64..95]). Loop
//    unrolled x2 so ring bases are compile-time.
//
// Schedule: 64 blocks (1/batch, 1 block/CU), 512 thr = 8 waves; waves 0-3 L1
// (16 units/wave), waves 4-7 L2 (8 units/wave). One barrier per step.
// amdgpu_waves_per_eu(2,2) keeps the 256-VGPR budget (round-4 finding).

#define BATCH 64
#define T 4096
#define NTHREADS 512
#define L2E 1.442695040888963f

__device__ __forceinline__ float fast_rcp(float v) { return __builtin_amdgcn_rcpf(v); }

// DPP cross-lane helpers (full-rate VALU, no LDS pipe).
// update_dpp(old=0, src, ctrl, row_mask, bank_mask, bound_ctrl=true)
__device__ __forceinline__ float dpp_qxor1(float v) {   // quad_perm [1,0,3,2]
    return __int_as_float(__builtin_amdgcn_update_dpp(0, __float_as_int(v), 0xB1, 0xF, 0xF, true));
}
__device__ __forceinline__ float dpp_qxor2(float v) {   // quad_perm [2,3,0,1]
    return __int_as_float(__builtin_amdgcn_update_dpp(0, __float_as_int(v), 0x4E, 0xF, 0xF, true));
}
__device__ __forceinline__ float dpp_shl4(float v) {    // lane i <- lane i+4 (row_shl:4)
    return __int_as_float(__builtin_amdgcn_update_dpp(0, __float_as_int(v), 0x104, 0xF, 0xF, true));
}
__device__ __forceinline__ float dpp_shr4(float v) {    // lane i <- lane i-4 (row_shr:4)
    return __int_as_float(__builtin_amdgcn_update_dpp(0, __float_as_int(v), 0x114, 0xF, 0xF, true));
}

// Barrier without the vmcnt(0) drain __syncthreads would emit.
#define LDS_BARRIER() do {                                   \
    asm volatile("s_waitcnt lgkmcnt(0)" ::: "memory");       \
    __builtin_amdgcn_s_barrier();                            \
    asm volatile("" ::: "memory");                           \
} while (0)

#define SIGM(v) fast_rcp(1.0f + exp2f(-L2E * (v)))

__global__ __launch_bounds__(NTHREADS)
__attribute__((amdgpu_waves_per_eu(2, 2)))
void lstm2_fused_v6b(const float* __restrict__ x,
                     const float* __restrict__ W_ih1, const float* __restrict__ W_hh1,
                     const float* __restrict__ b_ih1, const float* __restrict__ b_hh1,
                     const float* __restrict__ W_ih2, const float* __restrict__ W_hh2,
                     const float* __restrict__ b_ih2, const float* __restrict__ b_hh2,
                     float* __restrict__ out)
{
    const int b    = blockIdx.x;
    const int tid  = threadIdx.x;
    const int wave = tid >> 6;
    const int lane = tid & 63;
    const bool is_l1 = (wave < 4);
    const int kq = lane & 3;     // L1 K-quarter
    const int m8 = lane & 7;     // L2 K-octet

    __shared__ __align__(16) float hbuf[2][96];      // [ring][0..63]=h1, [64..95]=h2
    __shared__ __align__(16) float xbuf[2][64][4];   // 2-chunk x ring

    if (tid < 192) ((float*)hbuf)[tid] = 0.0f;

    // ---- per-lane weights in registers ----
    float w[4][17];      // L1: [g][0..15]=W_hh1 K-slice, [16]=W_ih1[kq]; L2: [g][0..11]=wcat slice
    float bini[4];       // bias (only slice-0 lane carries it)
    float c = 0.0f;
    int uidx;

    if (is_l1) {
        uidx = (wave << 4) + (lane >> 2);            // unit 0..63
#pragma unroll
        for (int g = 0; g < 4; ++g) {
            const int r = (g << 6) + uidx;           // gate row in [256]
            const float* row = W_hh1 + (size_t)r * 64 + (kq << 4);
#pragma unroll
            for (int k = 0; k < 16; ++k) w[g][k] = row[k];
            w[g][16] = W_ih1[r * 4 + kq];
            bini[g] = (kq == 0) ? (b_ih1[r] + b_hh1[r]) : 0.0f;
        }
    } else {
        uidx = ((wave - 4) << 3) + (lane >> 3);      // unit 0..31
#pragma unroll
        for (int g = 0; g < 4; ++g) {
            const int r = (g << 5) + uidx;           // gate row in [128]
#pragma unroll
            for (int k = 0; k < 12; ++k) {
                const int kk = 12 * m8 + k;          // position in concat [W_ih2(64)|W_hh2(32)]
                const float* src = (kk < 64) ? (W_ih2 + (size_t)r * 64 + kk)
                                             : (W_hh2 + (size_t)r * 32 + (kk - 64));
                w[g][k] = *src;
            }
            bini[g] = (m8 == 0) ? (b_ih2[r] + b_hh2[r]) : 0.0f;
        }
    }

    const float4* xptr = (const float4*)(x + (size_t)b * T * 4);
    float4 xg = make_float4(0.f, 0.f, 0.f, 0.f);
    if (wave == 0) {
        float4 x0 = xptr[lane];                      // chunk 0
        *(float4*)&xbuf[0][lane][0] = x0;
        xg = xptr[64 + lane];                        // chunk 1 in flight
    }
    float* outb = out + (size_t)b * T * 32;

    __syncthreads();                                  // full barrier once

#define STEP(nn, cur, prv)                                                        \
  do {                                                                            \
    if (is_l1) {                                                                  \
      if ((nn) < T) {                                                             \
        const int s = (nn) & 63;                                                  \
        if (s == 0 && wave == 0) {                                                \
            const int cch = (nn) >> 6;                                            \
            *(float4*)&xbuf[(cch + 1) & 1][lane][0] = xg;                         \
            const int nb = (cch + 2) << 6;                                        \
            if (nb < T) xg = xptr[nb + lane];                                     \
        }                                                                         \
        const float4* hv = (const float4*)&hbuf[prv][kq << 4];                    \
        const float4 ha = hv[0], hb = hv[1], hc = hv[2], hd = hv[3];              \
        const float xv = xbuf[((nn) >> 6) & 1][s][kq];                            \
        float hh[17] = { ha.x, ha.y, ha.z, ha.w, hb.x, hb.y, hb.z, hb.w,          \
                         hc.x, hc.y, hc.z, hc.w, hd.x, hd.y, hd.z, hd.w, xv };    \
        float p[4] = { bini[0], bini[1], bini[2], bini[3] };                      \
        _Pragma("unroll")                                                         \
        for (int g = 0; g < 4; ++g) {                                             \
            _Pragma("unroll")                                                     \
            for (int k = 0; k < 17; ++k) p[g] = fmaf(hh[k], w[g][k], p[g]);       \
        }                                                                         \
        _Pragma("unroll")                                                         \
        for (int g = 0; g < 4; ++g) {                                             \
            p[g] += dpp_qxor1(p[g]);                                              \
            p[g] += dpp_qxor2(p[g]);                                              \
        }                                                                         \
        const float gi = SIGM(p[0]);                                              \
        const float gf = SIGM(p[1]);                                              \
        const float gg = fmaf(2.0f, fast_rcp(1.0f + exp2f(-2.0f * L2E * p[2])), -1.0f); \
        const float go = SIGM(p[3]);                                              \
        c = fmaf(gf, c, gi * gg);                                                 \
        const float th = fmaf(-2.0f, fast_rcp(exp2f(2.0f * L2E * c) + 1.0f), 1.0f); \
        const float h = go * th;                                                  \
        if (kq == 0) hbuf[cur][uidx] = h;                                         \
      }                                                                           \
    } else {                                                                      \
      if ((nn) >= 1) {                                                            \
        const float* hp = &hbuf[prv][m8 * 12];       /* concat [h1|h2] slice */   \
        const float4 ca = *(const float4*)(hp + 0);                               \
        const float4 cb = *(const float4*)(hp + 4);                               \
        const float4 cc = *(const float4*)(hp + 8);                               \
        float hh[12] = { ca.x, ca.y, ca.z, ca.w, cb.x, cb.y, cb.z, cb.w,          \
                         cc.x, cc.y, cc.z, cc.w };                                \
        float p[4] = { bini[0], bini[1], bini[2], bini[3] };                      \
        _Pragma("unroll")                                                         \
        for (int g = 0; g < 4; ++g) {                                             \
            _Pragma("unroll")                                                     \
            for (int k = 0; k < 12; ++k) p[g] = fmaf(hh[k], w[g][k], p[g]);       \
        }                                                                         \
        _Pragma("unroll")                                                         \
        for (int g = 0; g < 4; ++g) {                                             \
            p[g] += dpp_qxor1(p[g]);                                              \
            p[g] += dpp_qxor2(p[g]);                                              \
            const float up = dpp_shl4(p[g]);   /* valid for (lane&4)==0 */        \
            const float dn = dpp_shr4(p[g]);   /* valid for (lane&4)!=0 */        \
            p[g] += (lane & 4) ? dn : up;                                         \
        }                                                                         \
        const float gi = SIGM(p[0]);                                              \
        const float gf = SIGM(p[1]);                                              \
        const float gg = fmaf(2.0f, fast_rcp(1.0f + exp2f(-2.0f * L2E * p[2])), -1.0f); \
        const float go = SIGM(p[3]);                                              \
        c = fmaf(gf, c, gi * gg);                                                 \
        const float th = fmaf(-2.0f, fast_rcp(exp2f(2.0f * L2E * c) + 1.0f), 1.0f); \
        const float h = go * th;                                                  \
        if (m8 == 0) {                                                            \
            hbuf[cur][64 + uidx] = h;                                             \
            outb[(size_t)((nn) - 1) * 32 + uidx] = h;                             \
        }                                                                         \
      }                                                                           \
    }                                                                             \
    LDS_BARRIER();                                                                \
  } while (0)

    for (int n = 0; n < T; n += 2) {
        STEP(n, 0, 1);
        STEP(n + 1, 1, 0);
    }
    STEP(T, 0, 1);       // final L2 step (computes t = T-1); L1 side folds away

#undef STEP
}

extern "C" void kernel_launch(void* const* d_in, const int* in_sizes, int n_in,
                              void* d_out, int out_size, void* d_ws, size_t ws_size,
                              hipStream_t stream) {
    const float* x     = (const float*)d_in[0];
    const float* W_ih1 = (const float*)d_in[1];
    const float* W_hh1 = (const float*)d_in[2];
    const float* b_ih1 = (const float*)d_in[3];
    const float* b_hh1 = (const float*)d_in[4];
    const float* W_ih2 = (const float*)d_in[5];
    const float* W_hh2 = (const float*)d_in[6];
    const float* b_ih2 = (const float*)d_in[7];
    const float* b_hh2 = (const float*)d_in[8];
    float* out = (float*)d_out;

    lstm2_fused_v6b<<<dim3(BATCH), dim3(NTHREADS), 0, stream>>>(
        x, W_ih1, W_hh1, b_ih1, b_hh1, W_ih2, W_hh2, b_ih2, b_hh2, out);
}